// Round 2
// baseline (343.835 us; speedup 1.0000x reference)
//
#include <hip/hip_runtime.h>
#include <hip/hip_bf16.h>

#define N 8192
#define D 64

typedef __attribute__((ext_vector_type(8))) short bf16x8;
typedef __attribute__((ext_vector_type(4))) float f32x4;

__device__ inline unsigned short f2b(float f) {
    __hip_bfloat16 h = __float2bfloat16(f);
    return __builtin_bit_cast(unsigned short, h);
}

// Kernel 1: convert X (fp32) -> Xb (bf16), sq[i] = ||x_i||^2, and per-block
// partial column sums Vp[block][64].
// 512 blocks x 256 threads; thread g handles float4 g = row (g>>4), cols 4*(g&15)..+3.
// Block covers 16 consecutive rows.
__global__ __launch_bounds__(256) void gk_prep(const float4* __restrict__ X4,
                                               ushort4* __restrict__ Xb4,
                                               float* __restrict__ sq,
                                               float* __restrict__ Vp) {
    __shared__ float cs[4][64];
    const int tid = threadIdx.x;
    const int g = blockIdx.x * 256 + tid;
    float4 v = X4[g];
    ushort4 b;
    b.x = f2b(v.x); b.y = f2b(v.y); b.z = f2b(v.z); b.w = f2b(v.w);
    Xb4[g] = b;

    // row norm: 16 consecutive threads cover one row (16 x float4)
    float ss = v.x * v.x + v.y * v.y + v.z * v.z + v.w * v.w;
    ss += __shfl_xor(ss, 8, 16);
    ss += __shfl_xor(ss, 4, 16);
    ss += __shfl_xor(ss, 2, 16);
    ss += __shfl_xor(ss, 1, 16);
    if ((tid & 15) == 0) sq[g >> 4] = ss;

    // partial column sums: within a wave, lanes {cq, cq+16, cq+32, cq+48}
    // hold the same col-quad cq for 4 different rows -> xor-reduce over 16,32.
    float4 cv = v;
    cv.x += __shfl_xor(cv.x, 16); cv.x += __shfl_xor(cv.x, 32);
    cv.y += __shfl_xor(cv.y, 16); cv.y += __shfl_xor(cv.y, 32);
    cv.z += __shfl_xor(cv.z, 16); cv.z += __shfl_xor(cv.z, 32);
    cv.w += __shfl_xor(cv.w, 16); cv.w += __shfl_xor(cv.w, 32);
    const int wave = tid >> 6;
    const int lane = tid & 63;
    if (lane < 16) *(float4*)&cs[wave][lane * 4] = cv;
    __syncthreads();
    if (tid < 64) Vp[blockIdx.x * 64 + tid] = cs[0][tid] + cs[1][tid] + cs[2][tid] + cs[3][tid];
}

// Kernel 2: S = sum(sq); V[c] = sum_b Vp[b][c]; Vsq = ||V||^2;
// mean(d2) = 2S/N - 2Vsq/N^2; c0 = 1/(2*ALPHA*mean). One block.
__global__ __launch_bounds__(256) void gk_finalize(const float* __restrict__ sq,
                                                   const float* __restrict__ Vp,
                                                   float* __restrict__ scal) {
    __shared__ float red[256];
    const int tid = threadIdx.x;

    float s = 0.f;
    for (int r = tid; r < N; r += 256) s += sq[r];
    red[tid] = s;
    __syncthreads();
    for (int off = 128; off > 0; off >>= 1) {
        if (tid < off) red[tid] += red[tid + off];
        __syncthreads();
    }
    const float S = red[0];
    __syncthreads();

    // column sums: 4 threads per column
    const int c = tid & 63, k = tid >> 6;
    float v = 0.f;
    for (int bb = k; bb < 512; bb += 4) v += Vp[bb * 64 + c];
    red[tid] = v;
    __syncthreads();
    float vsq_part = 0.f;
    if (tid < 64) {
        const float vc = red[tid] + red[tid + 64] + red[tid + 128] + red[tid + 192];
        vsq_part = vc * vc;
    }
    __syncthreads();
    red[tid] = vsq_part;
    __syncthreads();
    for (int off = 128; off > 0; off >>= 1) {
        if (tid < off) red[tid] += red[tid + off];
        __syncthreads();
    }
    if (tid == 0) {
        const float Vsq = red[0];
        const float fN = (float)N;
        const float mean = 2.f * S / fN - 2.f * Vsq / (fN * fN);
        scal[0] = 1.f / (2.f * mean);   // ALPHA = 1.0
    }
}

// Kernel 3: main. Block computes tile rows [i0_blk, +64) x cols [j0, +128) of
// the Gram matrix; 4 waves, each 16 rows x 128 cols via mfma_f32_16x16x32_bf16.
// C/D layout: col = lane&15 (=m), row = 4*(lane>>4)+r (=4q+r).
// out is exactly symmetric, so each lane WRITES ITS TILE TRANSPOSED:
// memory row = j0+16t+m, memory cols = i0+4q+{0..3} -> one dwordx4 per t.
__global__ __launch_bounds__(256) void gk_main(const unsigned short* __restrict__ Xb,
                                               const float* __restrict__ sq,
                                               const float* __restrict__ scal,
                                               float* __restrict__ out) {
    const int lane = threadIdx.x & 63;
    const int wave = threadIdx.x >> 6;
    const int i0 = blockIdx.x * 64 + wave * 16;
    const int j0 = blockIdx.y * 128;
    const int m = lane & 15;
    const int q = lane >> 4;   // 0..3
    const float c0 = scal[0];

    const bf16x8* Arow = reinterpret_cast<const bf16x8*>(Xb + (i0 + m) * D + 8 * q);
    const bf16x8 a0 = Arow[0];   // k in [8q, 8q+8)
    const bf16x8 a1 = Arow[4];   // k in [32+8q, ...)

    f32x4 acc[8];
    float sqj[8];
#pragma unroll
    for (int t = 0; t < 8; ++t) acc[t] = (f32x4){0.f, 0.f, 0.f, 0.f};

#pragma unroll
    for (int t = 0; t < 8; ++t) {
        const bf16x8* Brow =
            reinterpret_cast<const bf16x8*>(Xb + (j0 + t * 16 + m) * D + 8 * q);
        const bf16x8 b0 = Brow[0];
        const bf16x8 b1 = Brow[4];
        sqj[t] = sq[j0 + t * 16 + m];
        acc[t] = __builtin_amdgcn_mfma_f32_16x16x32_bf16(a0, b0, acc[t], 0, 0, 0);
        acc[t] = __builtin_amdgcn_mfma_f32_16x16x32_bf16(a1, b1, acc[t], 0, 0, 0);
    }

    float sqi[4];
#pragma unroll
    for (int r = 0; r < 4; ++r) sqi[r] = sq[i0 + 4 * q + r];

#pragma unroll
    for (int t = 0; t < 8; ++t) {
        const int row = j0 + t * 16 + m;        // memory row (transposed write)
        const float sj = sqj[t];
        float4 o;
#pragma unroll
        for (int r = 0; r < 4; ++r) {
            float d2 = __builtin_fmaf(acc[t][r], -2.0f, sqi[r] + sj);
            d2 = fmaxf(d2, 0.0f);
            (&o.x)[r] = __expf(-d2 * c0);
        }
        *(float4*)&out[(size_t)row * N + i0 + 4 * q] = o;
    }
}

extern "C" void kernel_launch(void* const* d_in, const int* in_sizes, int n_in,
                              void* d_out, int out_size, void* d_ws, size_t ws_size,
                              hipStream_t stream) {
    const float* X = (const float*)d_in[0];
    float* out = (float*)d_out;

    char* ws = (char*)d_ws;
    unsigned short* Xb = (unsigned short*)ws;                     // 1 MiB
    float* sq   = (float*)(ws + 1048576);                         // 32 KiB
    float* Vp   = (float*)(ws + 1048576 + 32768);                 // 512*64*4 = 128 KiB
    float* scal = (float*)(ws + 1048576 + 32768 + 131072);        // scalars

    gk_prep<<<512, 256, 0, stream>>>((const float4*)X, (ushort4*)Xb, sq, Vp);
    gk_finalize<<<1, 256, 0, stream>>>(sq, Vp, scal);

    dim3 grid(N / 64, N / 128);   // 128 x 64 blocks
    gk_main<<<grid, 256, 0, stream>>>(Xb, sq, scal, out);
}

// Round 3
// 328.409 us; speedup vs baseline: 1.0470x; 1.0470x over previous
//
#include <hip/hip_runtime.h>
#include <hip/hip_bf16.h>

#define N 8192
#define D 64

typedef __attribute__((ext_vector_type(8))) short bf16x8;
typedef __attribute__((ext_vector_type(4))) float f32x4;

__device__ inline unsigned short f2b(float f) {
    __hip_bfloat16 h = __float2bfloat16(f);
    return __builtin_bit_cast(unsigned short, h);
}

// Kernel 1: convert X (fp32) -> Xb (bf16), sq[i] = ||x_i||^2, and per-block
// partial column sums Vp[block][64].
__global__ __launch_bounds__(256) void gk_prep(const float4* __restrict__ X4,
                                               ushort4* __restrict__ Xb4,
                                               float* __restrict__ sq,
                                               float* __restrict__ Vp) {
    __shared__ float cs[4][64];
    const int tid = threadIdx.x;
    const int g = blockIdx.x * 256 + tid;
    float4 v = X4[g];
    ushort4 b;
    b.x = f2b(v.x); b.y = f2b(v.y); b.z = f2b(v.z); b.w = f2b(v.w);
    Xb4[g] = b;

    // row norm: 16 consecutive threads cover one row (16 x float4)
    float ss = v.x * v.x + v.y * v.y + v.z * v.z + v.w * v.w;
    ss += __shfl_xor(ss, 8, 16);
    ss += __shfl_xor(ss, 4, 16);
    ss += __shfl_xor(ss, 2, 16);
    ss += __shfl_xor(ss, 1, 16);
    if ((tid & 15) == 0) sq[g >> 4] = ss;

    // partial column sums
    float4 cv = v;
    cv.x += __shfl_xor(cv.x, 16); cv.x += __shfl_xor(cv.x, 32);
    cv.y += __shfl_xor(cv.y, 16); cv.y += __shfl_xor(cv.y, 32);
    cv.z += __shfl_xor(cv.z, 16); cv.z += __shfl_xor(cv.z, 32);
    cv.w += __shfl_xor(cv.w, 16); cv.w += __shfl_xor(cv.w, 32);
    const int wave = tid >> 6;
    const int lane = tid & 63;
    if (lane < 16) *(float4*)&cs[wave][lane * 4] = cv;
    __syncthreads();
    if (tid < 64) Vp[blockIdx.x * 64 + tid] = cs[0][tid] + cs[1][tid] + cs[2][tid] + cs[3][tid];
}

// Kernel 2: S = sum(sq); V[c] = sum_b Vp[b][c]; Vsq = ||V||^2;
// mean(d2) = 2S/N - 2Vsq/N^2; c0 = 1/(2*ALPHA*mean). One block.
__global__ __launch_bounds__(256) void gk_finalize(const float* __restrict__ sq,
                                                   const float* __restrict__ Vp,
                                                   float* __restrict__ scal) {
    __shared__ float red[256];
    const int tid = threadIdx.x;

    float s = 0.f;
    for (int r = tid; r < N; r += 256) s += sq[r];
    red[tid] = s;
    __syncthreads();
    for (int off = 128; off > 0; off >>= 1) {
        if (tid < off) red[tid] += red[tid + off];
        __syncthreads();
    }
    const float S = red[0];
    __syncthreads();

    const int c = tid & 63, k = tid >> 6;
    float v = 0.f;
    for (int bb = k; bb < 512; bb += 4) v += Vp[bb * 64 + c];
    red[tid] = v;
    __syncthreads();
    float vsq_part = 0.f;
    if (tid < 64) {
        const float vc = red[tid] + red[tid + 64] + red[tid + 128] + red[tid + 192];
        vsq_part = vc * vc;
    }
    __syncthreads();
    red[tid] = vsq_part;
    __syncthreads();
    for (int off = 128; off > 0; off >>= 1) {
        if (tid < off) red[tid] += red[tid + off];
        __syncthreads();
    }
    if (tid == 0) {
        const float Vsq = red[0];
        const float fN = (float)N;
        const float mean = 2.f * S / fN - 2.f * Vsq / (fN * fN);
        scal[0] = 1.f / (2.f * mean);   // ALPHA = 1.0
    }
}

// Kernel 3: main. Block = 64 rows x 128 cols; wave w owns rows [i0blk+16w, +16).
// MFMA C/D layout: value(row = i0+4q+r, col = j0+16t+m) in acc[t][r].
// Epilogue: exp -> wave-private LDS tile [16][132] (pad 132: 2 lanes/bank = free),
// then read back 2 rows/instr and store 512B contiguous per row, single-wave
// line coverage (4 full aligned 128B lines per row-chunk). No __syncthreads:
// each wave reads only its own LDS region.
__global__ __launch_bounds__(256) void gk_main(const unsigned short* __restrict__ Xb,
                                               const float* __restrict__ sq,
                                               const float* __restrict__ scal,
                                               float* __restrict__ out) {
    __shared__ float lds[4 * 16 * 132];
    const int lane = threadIdx.x & 63;
    const int wave = threadIdx.x >> 6;
    const int i0 = blockIdx.x * 64 + wave * 16;
    const int j0 = blockIdx.y * 128;
    const int m = lane & 15;
    const int q = lane >> 4;   // 0..3
    const float c0 = scal[0];
    float* myLds = lds + wave * (16 * 132);

    const bf16x8* Arow = reinterpret_cast<const bf16x8*>(Xb + (i0 + m) * D + 8 * q);
    const bf16x8 a0 = Arow[0];   // k in [8q, 8q+8)
    const bf16x8 a1 = Arow[4];   // k in [32+8q, ...)

    f32x4 acc[8];
    float sqj[8];
#pragma unroll
    for (int t = 0; t < 8; ++t) acc[t] = (f32x4){0.f, 0.f, 0.f, 0.f};

#pragma unroll
    for (int t = 0; t < 8; ++t) {
        const bf16x8* Brow =
            reinterpret_cast<const bf16x8*>(Xb + (j0 + t * 16 + m) * D + 8 * q);
        const bf16x8 b0 = Brow[0];
        const bf16x8 b1 = Brow[4];
        sqj[t] = sq[j0 + t * 16 + m];
        acc[t] = __builtin_amdgcn_mfma_f32_16x16x32_bf16(a0, b0, acc[t], 0, 0, 0);
        acc[t] = __builtin_amdgcn_mfma_f32_16x16x32_bf16(a1, b1, acc[t], 0, 0, 0);
    }

    float sqi[4];
#pragma unroll
    for (int r = 0; r < 4; ++r) sqi[r] = sq[i0 + 4 * q + r];

    // exp epilogue -> LDS (value at local row 4q+r, col 16t+m)
#pragma unroll
    for (int t = 0; t < 8; ++t) {
        const float sj = sqj[t];
#pragma unroll
        for (int r = 0; r < 4; ++r) {
            float d2 = __builtin_fmaf(acc[t][r], -2.0f, sqi[r] + sj);
            d2 = fmaxf(d2, 0.0f);
            myLds[(4 * q + r) * 132 + 16 * t + m] = __expf(-d2 * c0);
        }
    }

    // coalesced store: 2 rows x 512B per instruction, all from this wave
    const int c = lane & 31;
    const int h = lane >> 5;
#pragma unroll
    for (int s = 0; s < 8; ++s) {
        const int row = 2 * s + h;
        float4 v = *(const float4*)&myLds[row * 132 + 4 * c];
        *(float4*)&out[(size_t)(i0 + row) * N + j0 + 4 * c] = v;
    }
}

extern "C" void kernel_launch(void* const* d_in, const int* in_sizes, int n_in,
                              void* d_out, int out_size, void* d_ws, size_t ws_size,
                              hipStream_t stream) {
    const float* X = (const float*)d_in[0];
    float* out = (float*)d_out;

    char* ws = (char*)d_ws;
    unsigned short* Xb = (unsigned short*)ws;                     // 1 MiB
    float* sq   = (float*)(ws + 1048576);                         // 32 KiB
    float* Vp   = (float*)(ws + 1048576 + 32768);                 // 128 KiB
    float* scal = (float*)(ws + 1048576 + 32768 + 131072);        // scalars

    gk_prep<<<512, 256, 0, stream>>>((const float4*)X, (ushort4*)Xb, sq, Vp);
    gk_finalize<<<1, 256, 0, stream>>>(sq, Vp, scal);

    dim3 grid(N / 64, N / 128);   // 128 x 64 blocks
    gk_main<<<grid, 256, 0, stream>>>(Xb, sq, scal, out);
}